// Round 1
// 228.667 us; speedup vs baseline: 1.0493x; 1.0493x over previous
//
#include <hip/hip_runtime.h>
#include <hip/hip_bf16.h>
#include <math.h>

// Problem constants
#define BB   16
#define CIN  16
#define HH   320
#define WW   320
#define OUTC 16
#define KK   4
#define HID  5
#define HWSZ (HH * WW)        // 102400

// Conv tiling
#define TW   64               // tile width (pixels)
#define TH   16               // tile height (rows)
#define LROW 66               // LDS row width in pixels (64 + 2 halo)
#define LROWS 18              // TH + 2 halo
#define NPIX (LROWS * LROW)   // 1188 pixels per tile
#define NTASK (2 * NPIX)      // 2376 staging tasks (pixel x channel-half)
#define LDSN (2 * NPIX * 8)   // shorts: 19008 (38016 B)
#define KCH  5                // K chunks of 32 (K = 144 padded to 160)

// Prep kernel tiling: per (b,half): 102400 px / 4 = 25600 groups, 50 blocks
// of 512 groups (2 iters x 256 threads). 100 blocks per b, 1600 total.
#define K1_BLOCKS_PER_B 100
#define K1_GROUPS_PER_BLOCK 512

// Workspace layout (new path)
#define XT_BYTES      52428800ull   // 16*2*102400*8 shorts * 2B
#define PART_OFF      52428800ull   // 1600 blocks * 8 floats = 51200 B
#define ZPAGE_OFF     52480000ull   // 64 B zero page (16-B aligned)
#define WB_OFF        52480064ull   // 80 KB
#define WS_NEED       (WB_OFF + 81920ull)

typedef __attribute__((ext_vector_type(8))) short bf16x8_t;
typedef __attribute__((ext_vector_type(4))) float f32x4_t;

static __device__ __forceinline__ unsigned short f2bf(float f) {
    union { float f; unsigned u; } x; x.f = f;
    unsigned r = x.u + 0x7FFF + ((x.u >> 16) & 1);   // round-to-nearest-even
    return (unsigned short)(r >> 16);
}

// ---------------------------------------------------------------------------
// Kernel 1 (new): fused global-avg-pool partials + f32->bf16 transpose.
// Reads x once (float4), writes xT[b][half][pixel][8ch] bf16 (the exact
// 16-B slot format the conv kernel stages into LDS).
// Grid: 1600 blocks (16 b x 100), 256 threads.
// ---------------------------------------------------------------------------
__global__ __launch_bounds__(256)
void dg_prep_kernel(const float* __restrict__ x,
                    unsigned short* __restrict__ xT,
                    float* __restrict__ partials) {
    const int blk = blockIdx.x;                 // 0..1599
    const int b   = blk / K1_BLOCKS_PER_B;
    const int bib = blk - b * K1_BLOCKS_PER_B;  // 0..99
    const int half = (bib >= 50) ? 1 : 0;
    const int gbase = (bib - half * 50) * K1_GROUPS_PER_BLOCK;
    const int tid = threadIdx.x;

    const float* xb = x + ((size_t)(b * CIN + half * 8)) * HWSZ;
    unsigned short* xTb = xT + (((size_t)(b * 2 + half)) * HWSZ) * 8;

    float sums[8];
    #pragma unroll
    for (int c = 0; c < 8; ++c) sums[c] = 0.f;

    #pragma unroll 1
    for (int it = 0; it < 2; ++it) {
        const int g = gbase + it * 256 + tid;   // group index within half
        const int p0 = g * 4;                   // first pixel of group
        f32x4_t v[8];
        #pragma unroll
        for (int c = 0; c < 8; ++c) {
            v[c] = *(const f32x4_t*)(xb + (size_t)c * HWSZ + p0);
            sums[c] += (v[c][0] + v[c][1]) + (v[c][2] + v[c][3]);
        }
        #pragma unroll
        for (int j = 0; j < 4; ++j) {
            bf16x8_t o;
            #pragma unroll
            for (int c = 0; c < 8; ++c) o[c] = (short)f2bf(v[c][j]);
            *(bf16x8_t*)(xTb + ((size_t)(p0 + j) << 3)) = o;
        }
    }

    // reduce 8 channel partials across the block
    #pragma unroll
    for (int c = 0; c < 8; ++c) {
        float s = sums[c];
        #pragma unroll
        for (int off = 32; off > 0; off >>= 1) s += __shfl_down(s, off, 64);
        sums[c] = s;
    }
    __shared__ float red[4][8];
    if ((tid & 63) == 0) {
        #pragma unroll
        for (int c = 0; c < 8; ++c) red[tid >> 6][c] = sums[c];
    }
    __syncthreads();
    if (tid < 8) {
        float t = red[0][tid] + red[1][tid] + red[2][tid] + red[3][tid];
        partials[(size_t)blk * 8 + tid] = t;
    }
}

// ---------------------------------------------------------------------------
// Kernel 2 (new): finalize pool + attention MLP + scrambled softmax +
// expert mix, emitted in MFMA B-fragment lane order (bf16). Also (re)writes
// the 64-B zero page used by conv boundary staging (ws is re-poisoned by the
// harness between iterations, so this must happen every launch).
// One block per batch sample, 64 threads.
// ---------------------------------------------------------------------------
__global__ __launch_bounds__(64)
void dg_mix2_kernel(const float* __restrict__ partials,
                    const float* __restrict__ w1,
                    const float* __restrict__ w2,
                    const float* __restrict__ b2,
                    const float* __restrict__ weight,
                    unsigned short* __restrict__ wB,
                    float* __restrict__ zpage) {
    const int b = blockIdx.x;
    const int tid = threadIdx.x;   // 0..63
    __shared__ float pooledSh[16];
    __shared__ float sm[64];
    __shared__ float coeff[64];    // flat softmax, (k*16+o) order

    if (tid < 16) {
        const int half = tid >> 3;
        const float* pp = partials
            + ((size_t)(b * K1_BLOCKS_PER_B + half * 50)) * 8 + (tid & 7);
        float s = 0.f;
        #pragma unroll
        for (int i = 0; i < 50; ++i) s += pp[(size_t)i * 8];
        pooledSh[tid] = s * (1.f / (float)HWSZ);
    }
    if (b == 0 && tid < 16) zpage[tid] = 0.f;   // 64-B zero page
    __syncthreads();

    float pb[CIN];
    #pragma unroll
    for (int c = 0; c < CIN; ++c) pb[c] = pooledSh[c];
    float hid[HID];
    #pragma unroll
    for (int h = 0; h < HID; ++h) {
        float a = 0.f;
        #pragma unroll
        for (int c = 0; c < CIN; ++c) a = fmaf(pb[c], w1[h * CIN + c], a);
        hid[h] = fmaxf(a, 0.f);
    }
    float a = b2[tid];
    #pragma unroll
    for (int h = 0; h < HID; ++h) a = fmaf(hid[h], w2[tid * HID + h], a);
    sm[tid] = a;
    __syncthreads();

    const int oa = tid & 15;
    float a0 = sm[oa], a1 = sm[16 + oa], a2 = sm[32 + oa], a3 = sm[48 + oa];
    float m = fmaxf(fmaxf(a0, a1), fmaxf(a2, a3));
    float denom = expf(a0 - m) + expf(a1 - m) + expf(a2 - m) + expf(a3 - m);
    coeff[tid] = expf(sm[tid] - m) / denom;
    __syncthreads();

    const int o = tid & 15;
    const int kbase = (tid >> 4) * 8;
    #pragma unroll
    for (int kc = 0; kc < KCH; ++kc) {
        unsigned short frag[8];
        #pragma unroll
        for (int j = 0; j < 8; ++j) {
            const int k = kc * 32 + kbase + j;
            float v = 0.f;
            if (k < 144) {
                const int tap = k >> 4;
                const int c = k & 15;
                const float* wp = weight + (((size_t)(o * CIN + c) * 9 + tap) << 2);
                v = coeff[o * 4 + 0] * wp[0] + coeff[o * 4 + 1] * wp[1]
                  + coeff[o * 4 + 2] * wp[2] + coeff[o * 4 + 3] * wp[3];
            }
            frag[j] = f2bf(v);
        }
        unsigned short* dst = wB + (((size_t)(b * KCH + kc) * 64) + tid) * 8;
        #pragma unroll
        for (int j = 0; j < 8; ++j) dst[j] = frag[j];
    }
}

// ---------------------------------------------------------------------------
// Kernel 3 (new): implicit-GEMM conv via mfma_f32_16x16x32_bf16, staging
// pre-transposed bf16 slots with global_load_lds (16 B, linear LDS dest in
// task order). Boundary lanes redirect the per-lane GLOBAL source to the
// zero page. Tail iteration duplicates tasks (same data) to keep full exec.
// ---------------------------------------------------------------------------
__global__ __launch_bounds__(256, 4)
void dg_conv_bf16_kernel(const unsigned short* __restrict__ xT,
                         const unsigned short* __restrict__ wB,
                         const unsigned short* __restrict__ zpage,
                         float* __restrict__ out) {
    const int b   = blockIdx.z;
    const int by0 = blockIdx.y * TH;
    const int bx0 = blockIdx.x * TW;
    const int tid = threadIdx.x;
    const int lane = tid & 63;
    const int wave = tid >> 6;

    __shared__ __align__(16) unsigned short sx[LDSN];

    // ---- B fragments (per-lane, coalesced 16-B global loads; L2-resident) ----
    bf16x8_t Bf[KCH];
    {
        const unsigned short* wBb = wB + (size_t)b * KCH * 512;
        #pragma unroll
        for (int kc = 0; kc < KCH; ++kc)
            Bf[kc] = *(const bf16x8_t*)(wBb + kc * 512 + lane * 8);
    }

    // ---- stage xT tile -> LDS via global_load_lds (no VALU cvt, no ds_write) ----
    {
        const unsigned short* xTb = xT + (size_t)b * 2 * HWSZ * 8;
        #pragma unroll 1
        for (int it = 0; it < 10; ++it) {
            int t = tid + it * 256;
            if (t >= NTASK) t -= 256;           // duplicate tail tasks (same data)
            const int half = (t >= NPIX) ? 1 : 0;
            const int P    = t - half * NPIX;
            const int row  = P / LROW;
            const int px   = P - row * LROW;
            const int gy = by0 - 1 + row;
            const int gx = bx0 - 1 + px;
            const bool valid = ((unsigned)gy < HH) && ((unsigned)gx < WW);
            const int lin = gy * WW + gx;       // only used when valid
            const unsigned short* src = valid
                ? xTb + (((size_t)half * HWSZ + (size_t)lin) << 3)
                : zpage;
            __builtin_amdgcn_global_load_lds(
                (const __attribute__((address_space(1))) void*)src,
                (__attribute__((address_space(3))) void*)&sx[(size_t)t * 8],
                16, 0, 0);
        }
    }

    // ---- per-lane A-fragment addressing constants ----
    const int m     = lane & 15;
    const int quad  = lane >> 4;
    const int chalf = quad & 1;
    int dP[KCH];
    #pragma unroll
    for (int kc = 0; kc < KCH; ++kc) {
        int t = 2 * kc + (quad >> 1);
        if (t > 8) t = 8;                 // k>=144: B is zero, clamp tap to stay in tile
        dP[kc] = (t / 3 - 1) * LROW + (t % 3 - 1);
    }
    const int hofs = chalf * NPIX;        // slot offset for channel half

    f32x4_t acc[16];
    #pragma unroll
    for (int i = 0; i < 16; ++i) acc[i] = (f32x4_t){0.f, 0.f, 0.f, 0.f};

    __syncthreads();

    // ---- main MFMA loop: 4 rows x 4 x-tiles x 5 K-chunks ----
    #pragma unroll
    for (int rr = 0; rr < 4; ++rr) {
        #pragma unroll
        for (int tx = 0; tx < 4; ++tx) {
            const int P0 = (4 * wave + rr + 1) * LROW + 1 + tx * 16 + m;
            #pragma unroll
            for (int kc = 0; kc < KCH; ++kc) {
                const int S = hofs + P0 + dP[kc];
                const bf16x8_t Af = *(const bf16x8_t*)&sx[(size_t)S * 8];
                acc[rr * 4 + tx] = __builtin_amdgcn_mfma_f32_16x16x32_bf16(
                    Af, Bf[kc], acc[rr * 4 + tx], 0, 0, 0);
            }
        }
    }

    // ---- epilogue: D layout col=lane&15=outc n, row=quad*4+reg=pixel ----
    const int n = lane & 15;
    float* ob = out + ((size_t)(b * OUTC + n)) * HWSZ;
    #pragma unroll
    for (int rr = 0; rr < 4; ++rr) {
        const int gy = by0 + 4 * wave + rr;
        #pragma unroll
        for (int tx = 0; tx < 4; ++tx) {
            const int gx = bx0 + tx * 16 + quad * 4;
            *(f32x4_t*)(ob + (size_t)gy * WW + gx) = acc[rr * 4 + tx];
        }
    }
}

// ===========================================================================
// Fallback path (old pipeline) — used only if ws_size is too small for xT.
// ===========================================================================
__global__ __launch_bounds__(1024)
void dg_pool_kernel(const float* __restrict__ x, float* __restrict__ pooled) {
    const int plane = blockIdx.x;              // b*CIN + c, 0..255
    const float4* p4 = (const float4*)(x + (size_t)plane * HWSZ);
    float s = 0.f;
    #pragma unroll 5
    for (int i = threadIdx.x; i < HWSZ / 4; i += 1024) {
        float4 v = p4[i];
        s += (v.x + v.y) + (v.z + v.w);
    }
    #pragma unroll
    for (int off = 32; off > 0; off >>= 1) s += __shfl_down(s, off, 64);
    __shared__ float red[16];
    if ((threadIdx.x & 63) == 0) red[threadIdx.x >> 6] = s;
    __syncthreads();
    if (threadIdx.x == 0) {
        float t = 0.f;
        #pragma unroll
        for (int i = 0; i < 16; ++i) t += red[i];
        pooled[plane] = t * (1.f / (float)HWSZ);
    }
}

__global__ __launch_bounds__(64)
void dg_mix_kernel(const float* __restrict__ pooled,
                   const float* __restrict__ w1,
                   const float* __restrict__ w2,
                   const float* __restrict__ b2,
                   const float* __restrict__ weight,
                   unsigned short* __restrict__ wB) {
    const int b = blockIdx.x;
    const int tid = threadIdx.x;   // 0..63
    __shared__ float sm[64];
    __shared__ float coeff[64];

    float pb[CIN];
    #pragma unroll
    for (int c = 0; c < CIN; ++c) pb[c] = pooled[b * CIN + c];
    float hid[HID];
    #pragma unroll
    for (int h = 0; h < HID; ++h) {
        float a = 0.f;
        #pragma unroll
        for (int c = 0; c < CIN; ++c) a = fmaf(pb[c], w1[h * CIN + c], a);
        hid[h] = fmaxf(a, 0.f);
    }
    float a = b2[tid];
    #pragma unroll
    for (int h = 0; h < HID; ++h) a = fmaf(hid[h], w2[tid * HID + h], a);
    sm[tid] = a;
    __syncthreads();

    const int oa = tid & 15;
    float a0 = sm[oa], a1 = sm[16 + oa], a2 = sm[32 + oa], a3 = sm[48 + oa];
    float m = fmaxf(fmaxf(a0, a1), fmaxf(a2, a3));
    float denom = expf(a0 - m) + expf(a1 - m) + expf(a2 - m) + expf(a3 - m);
    coeff[tid] = expf(sm[tid] - m) / denom;
    __syncthreads();

    const int o = tid & 15;
    const int kbase = (tid >> 4) * 8;
    #pragma unroll
    for (int kc = 0; kc < KCH; ++kc) {
        unsigned short frag[8];
        #pragma unroll
        for (int j = 0; j < 8; ++j) {
            const int k = kc * 32 + kbase + j;
            float v = 0.f;
            if (k < 144) {
                const int tap = k >> 4;
                const int c = k & 15;
                const float* wp = weight + (((size_t)(o * CIN + c) * 9 + tap) << 2);
                v = coeff[o * 4 + 0] * wp[0] + coeff[o * 4 + 1] * wp[1]
                  + coeff[o * 4 + 2] * wp[2] + coeff[o * 4 + 3] * wp[3];
            }
            frag[j] = f2bf(v);
        }
        unsigned short* dst = wB + (((size_t)(b * KCH + kc) * 64) + tid) * 8;
        #pragma unroll
        for (int j = 0; j < 8; ++j) dst[j] = frag[j];
    }
}

__global__ __launch_bounds__(256, 4)
void dg_conv_kernel(const float* __restrict__ x,
                    const unsigned short* __restrict__ wB,
                    float* __restrict__ out) {
    const int b   = blockIdx.z;
    const int by0 = blockIdx.y * TH;
    const int bx0 = blockIdx.x * TW;
    const int tid = threadIdx.x;
    const int lane = tid & 63;
    const int wave = tid >> 6;

    __shared__ __align__(16) unsigned short sx[LDSN];

    bf16x8_t Bf[KCH];
    {
        const unsigned short* wBb = wB + (size_t)b * KCH * 512;
        #pragma unroll
        for (int kc = 0; kc < KCH; ++kc)
            Bf[kc] = *(const bf16x8_t*)(wBb + kc * 512 + lane * 8);
    }

    {
        const float* xb = x + (size_t)b * CIN * HWSZ;
        #pragma unroll 1
        for (int it = 0; it < 10; ++it) {
            const int t = tid + it * 256;
            if (t < NTASK) {
                const int half = (t >= NPIX) ? 1 : 0;
                const int P    = t - half * NPIX;
                const int row  = P / LROW;
                const int px   = P - row * LROW;
                const int gy = by0 - 1 + row;
                const int gx = bx0 - 1 + px;
                const bool valid = ((unsigned)gy < HH) && ((unsigned)gx < WW);
                const int gyc = valid ? gy : 0;
                const int gxc = valid ? gx : 0;
                const float* bp = xb + (size_t)(half * 8) * HWSZ
                                     + (size_t)gyc * WW + gxc;
                bf16x8_t v8;
                #pragma unroll
                for (int j = 0; j < 8; ++j) {
                    float v = valid ? bp[(size_t)j * HWSZ] : 0.f;
                    v8[j] = (short)f2bf(v);
                }
                *(bf16x8_t*)&sx[(size_t)t * 8] = v8;
            }
        }
    }

    const int m     = lane & 15;
    const int quad  = lane >> 4;
    const int chalf = quad & 1;
    int dP[KCH];
    #pragma unroll
    for (int kc = 0; kc < KCH; ++kc) {
        int t = 2 * kc + (quad >> 1);
        if (t > 8) t = 8;
        dP[kc] = (t / 3 - 1) * LROW + (t % 3 - 1);
    }
    const int hofs = chalf * NPIX;

    f32x4_t acc[16];
    #pragma unroll
    for (int i = 0; i < 16; ++i) acc[i] = (f32x4_t){0.f, 0.f, 0.f, 0.f};

    __syncthreads();

    #pragma unroll
    for (int rr = 0; rr < 4; ++rr) {
        #pragma unroll
        for (int tx = 0; tx < 4; ++tx) {
            const int P0 = (4 * wave + rr + 1) * LROW + 1 + tx * 16 + m;
            #pragma unroll
            for (int kc = 0; kc < KCH; ++kc) {
                const int S = hofs + P0 + dP[kc];
                const bf16x8_t Af = *(const bf16x8_t*)&sx[(size_t)S * 8];
                acc[rr * 4 + tx] = __builtin_amdgcn_mfma_f32_16x16x32_bf16(
                    Af, Bf[kc], acc[rr * 4 + tx], 0, 0, 0);
            }
        }
    }

    const int n = lane & 15;
    float* ob = out + ((size_t)(b * OUTC + n)) * HWSZ;
    #pragma unroll
    for (int rr = 0; rr < 4; ++rr) {
        const int gy = by0 + 4 * wave + rr;
        #pragma unroll
        for (int tx = 0; tx < 4; ++tx) {
            const int gx = bx0 + tx * 16 + quad * 4;
            *(f32x4_t*)(ob + (size_t)gy * WW + gx) = acc[rr * 4 + tx];
        }
    }
}

// ---------------------------------------------------------------------------
extern "C" void kernel_launch(void* const* d_in, const int* in_sizes, int n_in,
                              void* d_out, int out_size, void* d_ws, size_t ws_size,
                              hipStream_t stream) {
    const float* x      = (const float*)d_in[0];
    const float* w1     = (const float*)d_in[1];
    const float* w2     = (const float*)d_in[2];
    const float* b2     = (const float*)d_in[3];
    const float* weight = (const float*)d_in[4];
    float* out = (float*)d_out;

    if (ws_size >= WS_NEED) {
        // New path: single f32 read of x, bf16 transposed staging copy.
        unsigned short* xT       = (unsigned short*)d_ws;
        float*          partials = (float*)((char*)d_ws + PART_OFF);
        float*          zpage    = (float*)((char*)d_ws + ZPAGE_OFF);
        unsigned short* wBf      = (unsigned short*)((char*)d_ws + WB_OFF);

        dg_prep_kernel<<<BB * K1_BLOCKS_PER_B, 256, 0, stream>>>(x, xT, partials);
        dg_mix2_kernel<<<BB, 64, 0, stream>>>(partials, w1, w2, b2, weight, wBf, zpage);
        dg_conv_bf16_kernel<<<dim3(WW / TW, HH / TH, BB), 256, 0, stream>>>(
            xT, wBf, (const unsigned short*)zpage, out);
    } else {
        // Fallback: previous verified pipeline.
        float* pooled = (float*)d_ws;                                  // 256 floats
        unsigned short* wBf = (unsigned short*)((float*)d_ws + 256);   // 80 KB

        dg_pool_kernel<<<BB * CIN, 1024, 0, stream>>>(x, pooled);
        dg_mix_kernel<<<BB, 64, 0, stream>>>(pooled, w1, w2, b2, weight, wBf);
        dg_conv_kernel<<<dim3(WW / TW, HH / TH, BB), 256, 0, stream>>>(x, wBf, out);
    }
}